// Round 5
// baseline (692.873 us; speedup 1.0000x reference)
//
#include <hip/hip_runtime.h>

// ---------------- bf16 helpers (raw ushort storage) ----------------
__device__ __forceinline__ float b2f(unsigned short u) {
    union { unsigned int i; float f; } x; x.i = ((unsigned int)u) << 16; return x.f;
}
__device__ __forceinline__ unsigned short f2b(float f) {
    union { float f; unsigned int i; } x; x.f = f;
    unsigned int r = x.i + 0x7fffu + ((x.i >> 16) & 1u);   // RNE
    return (unsigned short)(r >> 16);
}
__device__ __forceinline__ bool finitef(float x) {
    union { float f; unsigned int u; } c; c.f = x;
    return ((c.u >> 23) & 0xffu) != 0xffu;
}

#define HDIM 128
#define WT_STRIDE 136   // ushorts; pad to reduce LDS bank conflicts on W reads

// ---------------- diagnostics ----------------
__global__ void fill_f32(float* p, int n, float v) {
    int i = blockIdx.x * 256 + threadIdx.x;
    if (i < n) p[i] = v;
}

// detect input float width: bf16 -> every ushort has sane exponent; fp32 -> even
// (low-half) ushorts are mantissa bits with ~uniform exponent field.
__global__ void detect_k(const unsigned short* __restrict__ x, int* __restrict__ flag) {
    __shared__ int sane;
    int tid = threadIdx.x;
    if (tid == 0) sane = 0;
    __syncthreads();
    unsigned short u = x[2 * tid];          // even indices = low halves if fp32
    int e = (u >> 7) & 0xff;
    if (e >= 100 && e <= 140) atomicAdd(&sane, 1);
    __syncthreads();
    if (tid == 0) { flag[0] = (sane >= 128) ? 1 : 0; flag[1] = 1; }  // flag[1]: const "bf16"
}

// normalize a small tensor to bf16 per detected flag
__global__ void norm_bf16(const unsigned short* __restrict__ src, unsigned short* __restrict__ dst,
                          int n, const int* __restrict__ flag) {
    int i = blockIdx.x * 256 + threadIdx.x;
    if (i >= n) return;
    if (flag[0]) dst[i] = src[i];
    else         dst[i] = f2b(((const float*)src)[i]);
}

// ---------------- edge normalization: int64-vs-int32 detect, compact to int32 ----------------
__global__ void edges_norm(const int* __restrict__ ei, int* __restrict__ s32,
                           int* __restrict__ d32, int E, int N) {
    __shared__ int sh;
    if (threadIdx.x == 0) {
        int acc = 0;
        for (int k = 1; k < 129; k += 2) acc |= ei[k];  // int64 => high words all 0
        sh = (acc == 0) ? 1 : 0;
    }
    __syncthreads();
    int is64 = sh;
    int e = blockIdx.x * 256 + threadIdx.x;
    if (e < E) {
        int s, d;
        if (is64) { s = ei[2 * (size_t)e]; d = ei[2 * (size_t)E + 2 * (size_t)e]; }
        else      { s = ei[e];             d = ei[(size_t)E + e]; }
        // clamp: if parse is wrong we stay finite & in-bounds (diagnosable, no fault)
        s = s < 0 ? 0 : (s >= N ? N - 1 : s);
        d = d < 0 ? 0 : (d >= N ? N - 1 : d);
        s32[e] = s; d32[e] = d;
    }
}

// ---------------- tiny utility kernels ----------------
__global__ void zero_i32(int* p, int n) {
    int i = blockIdx.x * 256 + threadIdx.x;
    if (i < n) p[i] = 0;
}

__global__ void hist_k(const int* __restrict__ dst, int* __restrict__ cnt, int E) {
    int e = blockIdx.x * 256 + threadIdx.x;
    if (e < E) atomicAdd(&cnt[dst[e]], 1);
}

__global__ void dinv_k(const int* __restrict__ cnt, float* __restrict__ dinv, int n) {
    int i = blockIdx.x * 256 + threadIdx.x;
    if (i < n) {
        int c = cnt[i]; c = c < 0 ? 0 : c;
        dinv[i] = rsqrtf((float)c + 1.0f);  // +1 self-loop
    }
}

// ---------------- exclusive scan over cnt[N] (N <= 65536) ----------------
__global__ void scan1(const int* __restrict__ cnt, int* __restrict__ bsum, int n) {
    __shared__ int sh[256];
    int t = threadIdx.x;
    int i = blockIdx.x * 256 + t;
    sh[t] = (i < n) ? cnt[i] : 0;
    __syncthreads();
    for (int s = 128; s > 0; s >>= 1) {
        if (t < s) sh[t] += sh[t + s];
        __syncthreads();
    }
    if (t == 0) bsum[blockIdx.x] = sh[0];
}

__global__ void scan2(int* bsum, int nblk) {   // single block, nblk <= 256
    __shared__ int sh[256];
    int t = threadIdx.x;
    sh[t] = (t < nblk) ? bsum[t] : 0;
    __syncthreads();
    for (int off = 1; off < 256; off <<= 1) {
        int v = (t >= off) ? sh[t - off] : 0;
        __syncthreads();
        sh[t] += v;
        __syncthreads();
    }
    if (t < nblk) bsum[t] = (t == 0) ? 0 : sh[t - 1];  // exclusive
}

__global__ void scan3(const int* __restrict__ cnt, const int* __restrict__ bsum,
                      int* __restrict__ start, int* __restrict__ cursor, int n) {
    __shared__ int sh[256];
    int t = threadIdx.x;
    int i = blockIdx.x * 256 + t;
    int v = (i < n) ? cnt[i] : 0;
    sh[t] = v;
    __syncthreads();
    for (int off = 1; off < 256; off <<= 1) {
        int a = (t >= off) ? sh[t - off] : 0;
        __syncthreads();
        sh[t] += a;
        __syncthreads();
    }
    if (i < n) {
        int excl = sh[t] - v + bsum[blockIdx.x];
        start[i] = excl;
        cursor[i] = excl;
    }
}

__global__ void scatter_k(const int* __restrict__ s32, const int* __restrict__ d32,
                          int* __restrict__ cursor, int* __restrict__ csr, int E) {
    int e = blockIdx.x * 256 + threadIdx.x;
    if (e < E) {
        int slot = atomicAdd(&cursor[d32[e]], 1);
        csr[slot] = s32[e];
    }
}

// ---------------- GEMM (VALU): C[n,128] = A[n,128] @ W[128,128], bf16 out ----------------
__global__ __launch_bounds__(256) void gemm_valu(const unsigned short* __restrict__ A,
                                                 const int* __restrict__ aflag,
                                                 const unsigned short* __restrict__ Wn,
                                                 unsigned short* __restrict__ C, int n) {
    __shared__ __align__(16) unsigned short Wt[128 * WT_STRIDE];
    __shared__ __align__(16) unsigned short Al[64 * 128];
    int tid = threadIdx.x;
    int row0 = blockIdx.x * 64;

    for (int it = 0; it < 64; ++it) {
        int idx = tid + it * 256;
        int k = idx >> 7, c = idx & 127;
        Wt[c * WT_STRIDE + k] = Wn[idx];
    }

    if (aflag[0]) {  // bf16 input
        const uint4* Ag = (const uint4*)A;
        uint4* Al4 = (uint4*)Al;
        for (int it = 0; it < 4; ++it) {
            int idx = tid + it * 256;
            int r = idx >> 4, cc = idx & 15;
            int gr = row0 + r;
            uint4 v; v.x = v.y = v.z = v.w = 0u;
            if (gr < n) v = Ag[(size_t)gr * 16 + cc];
            Al4[idx] = v;
        }
    } else {         // fp32 input -> convert
        const uint4* Af = (const uint4*)A;
        for (int it = 0; it < 8; ++it) {
            int idx = tid + it * 256;
            int r = idx >> 5, c4 = idx & 31;
            int gr = row0 + r;
            uint4 v; v.x = v.y = v.z = v.w = 0u;
            if (gr < n) v = Af[(size_t)gr * 32 + c4];
            float ff[4]; *(uint4*)ff = v;
            ushort4 o;
            o.x = f2b(ff[0]); o.y = f2b(ff[1]); o.z = f2b(ff[2]); o.w = f2b(ff[3]);
            *(ushort4*)&Al[r * 128 + c4 * 4] = o;
        }
    }
    __syncthreads();

    int c = tid & 127, u = tid >> 7;
    const uint4* Al4 = (const uint4*)Al;
    const uint4* Wt4 = (const uint4*)Wt;

    float acc[32];
#pragma unroll
    for (int rr = 0; rr < 32; ++rr) acc[rr] = 0.f;

    for (int k8 = 0; k8 < 16; ++k8) {
        uint4 wv = Wt4[c * 17 + k8];
        unsigned short ws[8]; *(uint4*)ws = wv;
        float wf[8];
#pragma unroll
        for (int j = 0; j < 8; ++j) wf[j] = b2f(ws[j]);
#pragma unroll
        for (int rr = 0; rr < 32; ++rr) {
            uint4 av = Al4[(rr * 2 + u) * 16 + k8];
            unsigned short as[8]; *(uint4*)as = av;
#pragma unroll
            for (int j = 0; j < 8; ++j) acc[rr] += b2f(as[j]) * wf[j];
        }
    }

#pragma unroll
    for (int rr = 0; rr < 32; ++rr) {
        int gr = row0 + rr * 2 + u;
        if (gr < n) C[(size_t)gr * 128 + c] = f2b(acc[rr]);
    }
}

// ---------------- aggregation + fused BN column stats ----------------
__global__ __launch_bounds__(256) void agg_stats(
    const unsigned short* __restrict__ Hb, const float* __restrict__ dinv,
    const int* __restrict__ start, const int* __restrict__ cnt,
    const int* __restrict__ csr, unsigned short* __restrict__ AGG,
    float* __restrict__ colsum, float* __restrict__ colsq, int n) {
    int tid = threadIdx.x;
    int u = tid >> 7, f = tid & 127;
    float s1 = 0.f, s2 = 0.f;
    for (int i = blockIdx.x * 2 + u; i < n; i += gridDim.x * 2) {
        float di = dinv[i];
        float acc = b2f(Hb[(size_t)i * 128 + f]) * di;   // self-loop (x di at end)
        int s0 = start[i];
        int c = cnt[i];
        for (int e = 0; e < c; ++e) {
            int s = csr[s0 + e];
            s = s < 0 ? 0 : (s >= n ? n - 1 : s);         // stay in-bounds if csr corrupt
            acc += b2f(Hb[(size_t)s * 128 + f]) * dinv[s];
        }
        float v = acc * di;                               // norm = dinv[src]*dinv[dst]
        AGG[(size_t)i * 128 + f] = f2b(v);
        s1 += v;
        s2 += v * v;
    }
    __shared__ float red[256];
    red[tid] = s1; __syncthreads();
    if (u == 0) atomicAdd(&colsum[f], red[f] + red[f + 128]);
    __syncthreads();
    red[tid] = s2; __syncthreads();
    if (u == 0) atomicAdd(&colsq[f], red[f] + red[f + 128]);
}

// ---------------- BN finalize (with in-band diagnostics) ----------------
__global__ void bn_fin(const float* __restrict__ colsum, const float* __restrict__ colsq,
                       const unsigned short* __restrict__ g, const unsigned short* __restrict__ beta,
                       const int* __restrict__ flag,
                       float* __restrict__ scale, float* __restrict__ shift, float invn) {
    int f = threadIdx.x;
    if (f >= 128) return;
    float cs = colsum[f], cq = colsq[f];
    if (!finitef(cs) || !finitef(cq)) { scale[f] = 0.f; shift[f] = 150.f; return; }  // NaN upstream
    if (cq == 0.f)                    { scale[f] = 0.f; shift[f] = 200.f; return; }  // all-zero input
    float gv, bv;
    if (flag[0]) { gv = b2f(g[f]);            bv = b2f(beta[f]); }
    else         { gv = ((const float*)g)[f]; bv = ((const float*)beta)[f]; }
    float mu = cs * invn;
    float var = cq * invn - mu * mu;
    var = var < 0.f ? 0.f : var;
    float rstd = rsqrtf(var + 1e-5f);
    float s = gv * rstd;
    scale[f] = s;
    shift[f] = bv - mu * s;
}

// layer-1 apply: bf16 activation into ws
__global__ void bn_apply_b16(const unsigned short* __restrict__ AGG, const float* __restrict__ scale,
                             const float* __restrict__ shift, unsigned short* __restrict__ out,
                             int total) {
    int i = blockIdx.x * 256 + threadIdx.x;
    if (i < total) {
        int f = i & 127;
        float v = b2f(AGG[i]) * scale[f] + shift[f];
        if (!finitef(v)) v = 170.f;
        out[i] = f2b(v > 0.f ? v : 0.f);
    }
}

// layer-2 apply: fp32 to d_out (reference output dtype is float32)
__global__ void bn_apply_f32(const unsigned short* __restrict__ AGG, const float* __restrict__ scale,
                             const float* __restrict__ shift, float* __restrict__ out,
                             int total) {
    int i = blockIdx.x * 256 + threadIdx.x;
    if (i < total) {
        int f = i & 127;
        float v = b2f(AGG[i]) * scale[f] + shift[f];
        if (!finitef(v)) v = 170.f;
        out[i] = v > 0.f ? v : 0.f;
    }
}

// ---------------- launch ----------------
extern "C" void kernel_launch(void* const* d_in, const int* in_sizes, int n_in,
                              void* d_out, int out_size, void* d_ws, size_t ws_size,
                              hipStream_t stream) {
    const unsigned short* X0 = (const unsigned short*)d_in[0];
    const int* ei = (const int*)d_in[1];
    const unsigned short* W1 = (const unsigned short*)d_in[2];
    const unsigned short* W2 = (const unsigned short*)d_in[4];
    const unsigned short* g1 = (const unsigned short*)d_in[6];
    const unsigned short* be1 = (const unsigned short*)d_in[7];
    const unsigned short* g2 = (const unsigned short*)d_in[8];
    const unsigned short* be2 = (const unsigned short*)d_in[9];
    float* OUT = (float*)d_out;

    int N = in_sizes[0] / HDIM;
    int E = in_sizes[1] / 2;
    int total = N * HDIM;
    int applyb = (total + 255) / 256;

    // sentinel +50: survives iff the tail never runs
    fill_f32<<<applyb, 256, 0, stream>>>(OUT, total, 50.0f);

    // contract check -> -100
    bool ok = (n_in == 10) && (N > 0) && (in_sizes[0] == N * HDIM) && (E > 0)
           && (in_sizes[2] == HDIM * HDIM) && (in_sizes[4] == HDIM * HDIM)
           && (in_sizes[6] == HDIM) && (in_sizes[9] == HDIM) && (out_size == total);
    if (!ok) { fill_f32<<<applyb, 256, 0, stream>>>(OUT, total, -100.0f); return; }

    // workspace: cnt/start/cursor/dinv + bsum + stats + flags + s32/d32/csr + Hb + AGG + Xmid + Wn
    size_t need = (size_t)N * 16 + 1024 + 2048 + 16 + (size_t)E * 12
                + (size_t)total * 2 * 3 + (size_t)HDIM * HDIM * 2 * 2;
    if (ws_size < need) { fill_f32<<<applyb, 256, 0, stream>>>(OUT, total, -300.0f); return; }

    char* w = (char*)d_ws;
    int* cnt = (int*)w;       w += (size_t)N * 4;
    int* start = (int*)w;     w += (size_t)N * 4;
    int* cursor = (int*)w;    w += (size_t)N * 4;
    float* dinv = (float*)w;  w += (size_t)N * 4;
    int* bsum = (int*)w;      w += 1024;
    float* stats = (float*)w; w += 2048;            // colsum|colsq|scale|shift
    int* flags = (int*)w;     w += 16;
    int* s32 = (int*)w;       w += (size_t)E * 4;
    int* d32 = (int*)w;       w += (size_t)E * 4;
    int* csr = (int*)w;       w += (size_t)E * 4;
    unsigned short* Hb = (unsigned short*)w;   w += (size_t)total * 2;
    unsigned short* AGG = (unsigned short*)w;  w += (size_t)total * 2;
    unsigned short* Xmid = (unsigned short*)w; w += (size_t)total * 2;
    unsigned short* Wn1 = (unsigned short*)w;  w += (size_t)HDIM * HDIM * 2;
    unsigned short* Wn2 = (unsigned short*)w;  w += (size_t)HDIM * HDIM * 2;

    float* colsum = stats;
    float* colsq = stats + 128;
    float* scale = stats + 256;
    float* shift = stats + 384;

    int nb = (N + 255) / 256;
    int ebl = (E + 255) / 256;
    int gemmb = (N + 63) / 64;
    float invn = 1.0f / (float)N;

    // dtype detection + weight normalization
    detect_k<<<1, 256, 0, stream>>>(X0, flags);
    norm_bf16<<<64, 256, 0, stream>>>(W1, Wn1, HDIM * HDIM, flags);
    norm_bf16<<<64, 256, 0, stream>>>(W2, Wn2, HDIM * HDIM, flags);

    // graph structure (shared by both layers)
    edges_norm<<<ebl, 256, 0, stream>>>(ei, s32, d32, E, N);
    zero_i32<<<nb, 256, 0, stream>>>(cnt, N);
    zero_i32<<<1, 256, 0, stream>>>((int*)stats, 256);
    hist_k<<<ebl, 256, 0, stream>>>(d32, cnt, E);
    dinv_k<<<nb, 256, 0, stream>>>(cnt, dinv, N);
    scan1<<<nb, 256, 0, stream>>>(cnt, bsum, N);
    scan2<<<1, 256, 0, stream>>>(bsum, nb);
    scan3<<<nb, 256, 0, stream>>>(cnt, bsum, start, cursor, N);
    scatter_k<<<ebl, 256, 0, stream>>>(s32, d32, cursor, csr, E);

    // layer 1
    gemm_valu<<<gemmb, 256, 0, stream>>>(X0, flags, Wn1, Hb, N);
    agg_stats<<<2048, 256, 0, stream>>>(Hb, dinv, start, cnt, csr, AGG, colsum, colsq, N);
    bn_fin<<<1, 256, 0, stream>>>(colsum, colsq, g1, be1, flags, scale, shift, invn);
    bn_apply_b16<<<applyb, 256, 0, stream>>>(AGG, scale, shift, Xmid, total);
    zero_i32<<<1, 256, 0, stream>>>((int*)stats, 256);

    // layer 2 (Xmid is bf16 -> flags+1 is const 1)
    gemm_valu<<<gemmb, 256, 0, stream>>>(Xmid, flags + 1, Wn2, Hb, N);
    agg_stats<<<2048, 256, 0, stream>>>(Hb, dinv, start, cnt, csr, AGG, colsum, colsq, N);
    bn_fin<<<1, 256, 0, stream>>>(colsum, colsq, g2, be2, flags, scale, shift, invn);

    // probe: 0x4C pattern (~5.3e7) over first 256 floats; overwritten iff kernels execute.
    hipMemsetAsync(d_out, 0x4C, 1024, stream);
    bn_apply_f32<<<applyb, 256, 0, stream>>>(AGG, scale, shift, OUT, total);
}

// Round 6
// 403.360 us; speedup vs baseline: 1.7178x; 1.7178x over previous
//
#include <hip/hip_runtime.h>

// ---------------- bf16 helpers (raw ushort storage) ----------------
__device__ __forceinline__ float b2f(unsigned short u) {
    union { unsigned int i; float f; } x; x.i = ((unsigned int)u) << 16; return x.f;
}
__device__ __forceinline__ unsigned short f2b(float f) {
    union { float f; unsigned int i; } x; x.f = f;
    unsigned int r = x.i + 0x7fffu + ((x.i >> 16) & 1u);   // RNE
    return (unsigned short)(r >> 16);
}
__device__ __forceinline__ bool finitef(float x) {
    union { float f; unsigned int u; } c; c.f = x;
    return ((c.u >> 23) & 0xffu) != 0xffu;
}

typedef __attribute__((ext_vector_type(8))) __bf16 bf16x8;
typedef __attribute__((ext_vector_type(4))) float f32x4;

#define HDIM 128
#define LSTR 136   // LDS row stride (ushorts): 128+8 pad -> 2-way b128 conflicts only (free)

// ---------------- failure-path fill ----------------
__global__ void fill_f32(float* p, int n, float v) {
    int i = blockIdx.x * 256 + threadIdx.x;
    if (i < n) p[i] = v;
}

// detect input float width: bf16 -> sane exponent in every ushort; fp32 -> low halves random
__global__ void detect_k(const unsigned short* __restrict__ x, int* __restrict__ flag) {
    __shared__ int sane;
    int tid = threadIdx.x;
    if (tid == 0) sane = 0;
    __syncthreads();
    unsigned short u = x[2 * tid];
    int e = (u >> 7) & 0xff;
    if (e >= 100 && e <= 140) atomicAdd(&sane, 1);
    __syncthreads();
    if (tid == 0) flag[0] = (sane >= 128) ? 1 : 0;
}

// normalize W to bf16 AND transpose: dst[n*128+k] = W[k][n]   (16384 elems, 64 blocks)
__global__ void norm_w_t(const unsigned short* __restrict__ src, unsigned short* __restrict__ dst,
                         const int* __restrict__ flag) {
    int idx = blockIdx.x * 256 + threadIdx.x;
    int k = idx >> 7, c = idx & 127;
    unsigned short v;
    if (flag[0]) v = src[idx];
    else         v = f2b(((const float*)src)[idx]);
    dst[c * 128 + k] = v;
}

// ---------------- edges: int64/int32 detect, compact, clamp, fused degree histogram ----------------
__global__ void edges_norm(const int* __restrict__ ei, int* __restrict__ s32,
                           int* __restrict__ d32, int* __restrict__ cnt, int E, int N) {
    __shared__ int sh;
    if (threadIdx.x == 0) {
        int acc = 0;
        for (int k = 1; k < 129; k += 2) acc |= ei[k];  // int64 => high words all 0
        sh = (acc == 0) ? 1 : 0;
    }
    __syncthreads();
    int is64 = sh;
    int e = blockIdx.x * 256 + threadIdx.x;
    if (e < E) {
        int s, d;
        if (is64) { s = ei[2 * (size_t)e]; d = ei[2 * (size_t)E + 2 * (size_t)e]; }
        else      { s = ei[e];             d = ei[(size_t)E + e]; }
        s = s < 0 ? 0 : (s >= N ? N - 1 : s);
        d = d < 0 ? 0 : (d >= N ? N - 1 : d);
        s32[e] = s; d32[e] = d;
        atomicAdd(&cnt[d], 1);
    }
}

__global__ void zero_i32(int* p, int n) {
    int i = blockIdx.x * 256 + threadIdx.x;
    if (i < n) p[i] = 0;
}

__global__ void dinv_k(const int* __restrict__ cnt, float* __restrict__ dinv, int n) {
    int i = blockIdx.x * 256 + threadIdx.x;
    if (i < n) {
        int c = cnt[i]; c = c < 0 ? 0 : c;
        dinv[i] = rsqrtf((float)c + 1.0f);
    }
}

// ---------------- exclusive scan over cnt[N] ----------------
__global__ void scan1(const int* __restrict__ cnt, int* __restrict__ bsum, int n) {
    __shared__ int sh[256];
    int t = threadIdx.x;
    int i = blockIdx.x * 256 + t;
    sh[t] = (i < n) ? cnt[i] : 0;
    __syncthreads();
    for (int s = 128; s > 0; s >>= 1) {
        if (t < s) sh[t] += sh[t + s];
        __syncthreads();
    }
    if (t == 0) bsum[blockIdx.x] = sh[0];
}

__global__ void scan2(int* bsum, int nblk) {
    __shared__ int sh[256];
    int t = threadIdx.x;
    sh[t] = (t < nblk) ? bsum[t] : 0;
    __syncthreads();
    for (int off = 1; off < 256; off <<= 1) {
        int v = (t >= off) ? sh[t - off] : 0;
        __syncthreads();
        sh[t] += v;
        __syncthreads();
    }
    if (t < nblk) bsum[t] = (t == 0) ? 0 : sh[t - 1];
}

__global__ void scan3(const int* __restrict__ cnt, const int* __restrict__ bsum,
                      int* __restrict__ start, int* __restrict__ cursor, int n) {
    __shared__ int sh[256];
    int t = threadIdx.x;
    int i = blockIdx.x * 256 + t;
    int v = (i < n) ? cnt[i] : 0;
    sh[t] = v;
    __syncthreads();
    for (int off = 1; off < 256; off <<= 1) {
        int a = (t >= off) ? sh[t - off] : 0;
        __syncthreads();
        sh[t] += a;
        __syncthreads();
    }
    if (i < n) {
        int excl = sh[t] - v + bsum[blockIdx.x];
        start[i] = excl;
        cursor[i] = excl;
    }
}

__global__ void scatter_k(const int* __restrict__ s32, const int* __restrict__ d32,
                          int* __restrict__ cursor, int* __restrict__ csr, int E) {
    int e = blockIdx.x * 256 + threadIdx.x;
    if (e < E) {
        int slot = atomicAdd(&cursor[d32[e]], 1);
        csr[slot] = s32[e];
    }
}

// ---------------- GEMM (MFMA 16x16x32 bf16): C[n,128] = A[n,128] @ W ----------------
// Wt is pre-transposed W: Wt[nn*128+k] = W[k][nn].
// mode -1: A dtype per aflag (fp32 or bf16). mode 2: A = AGG bf16 with fused BN+ReLU staging.
__global__ __launch_bounds__(256) void gemm_mfma(
    const unsigned short* __restrict__ A, const unsigned short* __restrict__ Wt,
    unsigned short* __restrict__ C, const int* __restrict__ aflag, int mode,
    const float* __restrict__ scale, const float* __restrict__ shift, int n) {
    __shared__ __align__(16) unsigned short Wl[128 * LSTR];  // [nn][k] padded
    __shared__ __align__(16) unsigned short Al[64 * LSTR];   // [r][k] padded
    int tid = threadIdx.x;
    int row0 = blockIdx.x * 64;

    // stage Wt rows (2048 uint4, all-vector)
    const uint4* Wg = (const uint4*)Wt;
#pragma unroll
    for (int it = 0; it < 8; ++it) {
        int idx = tid + it * 256;
        int nn = idx >> 4, k8 = idx & 15;
        *(uint4*)&Wl[nn * LSTR + k8 * 8] = Wg[idx];
    }

    int amode = (mode == 2) ? 2 : aflag[0];   // 2=bn-fused bf16, 1=bf16, 0=fp32
    if (amode == 1) {
        const uint4* Ag = (const uint4*)A;
        for (int it = 0; it < 4; ++it) {
            int idx = tid + it * 256;
            int r = idx >> 4, cc = idx & 15;
            int gr = row0 + r;
            uint4 v; v.x = v.y = v.z = v.w = 0u;
            if (gr < n) v = Ag[(size_t)gr * 16 + cc];
            *(uint4*)&Al[r * LSTR + cc * 8] = v;
        }
    } else if (amode == 0) {   // fp32 -> bf16
        const uint4* Af = (const uint4*)A;
        for (int it = 0; it < 8; ++it) {
            int idx = tid + it * 256;
            int r = idx >> 5, c4 = idx & 31;
            int gr = row0 + r;
            uint4 v; v.x = v.y = v.z = v.w = 0u;
            if (gr < n) v = Af[(size_t)gr * 32 + c4];
            float ff[4]; *(uint4*)ff = v;
            ushort4 o;
            o.x = f2b(ff[0]); o.y = f2b(ff[1]); o.z = f2b(ff[2]); o.w = f2b(ff[3]);
            *(ushort4*)&Al[r * LSTR + c4 * 4] = o;
        }
    } else {                   // amode 2: AGG bf16 + BN + ReLU
        const uint4* Ag = (const uint4*)A;
        for (int it = 0; it < 4; ++it) {
            int idx = tid + it * 256;
            int r = idx >> 4, cc = idx & 15;
            int gr = row0 + r;
            uint4 v; v.x = v.y = v.z = v.w = 0u;
            if (gr < n) v = Ag[(size_t)gr * 16 + cc];
            unsigned short hu[8]; *(uint4*)hu = v;
            unsigned short ou[8];
#pragma unroll
            for (int j = 0; j < 8; ++j) {
                int f = cc * 8 + j;
                float x = b2f(hu[j]) * scale[f] + shift[f];
                ou[j] = f2b(x > 0.f ? x : 0.f);
            }
            *(uint4*)&Al[r * LSTR + cc * 8] = *(uint4*)ou;
        }
    }
    __syncthreads();

    int wave = tid >> 6, lane = tid & 63;
    int m = lane & 15, quad = lane >> 4;

    // A-frag: A[row = wave*16+m][k = kc*32 + quad*8 + j]
    bf16x8 afr[4];
#pragma unroll
    for (int kc = 0; kc < 4; ++kc)
        afr[kc] = *(const bf16x8*)&Al[(wave * 16 + m) * LSTR + kc * 32 + quad * 8];

    for (int t = 0; t < 8; ++t) {
        f32x4 acc = {0.f, 0.f, 0.f, 0.f};
#pragma unroll
        for (int kc = 0; kc < 4; ++kc) {
            // B-frag: B[k][nn = t*16+m] = Wl[nn][k], contiguous in k
            bf16x8 bfr = *(const bf16x8*)&Wl[(t * 16 + m) * LSTR + kc * 32 + quad * 8];
            acc = __builtin_amdgcn_mfma_f32_16x16x32_bf16(afr[kc], bfr, acc, 0, 0, 0);
        }
        // C/D: col = lane&15, row = quad*4 + reg (m89-verified)
#pragma unroll
        for (int i2 = 0; i2 < 4; ++i2) {
            int gr = row0 + wave * 16 + quad * 4 + i2;
            if (gr < n) C[(size_t)gr * 128 + t * 16 + m] = f2b(acc[i2]);
        }
    }
}

// ---------------- aggregation + fused BN column stats ----------------
// 1 wave per node; 4 groups x 16 lanes; each lane gathers uint4 (8 bf16 feats).
// Group g handles items t = g, g+4, ... where t=0 is the self-loop.
__global__ __launch_bounds__(256) void agg_stats(
    const unsigned short* __restrict__ Hb, const float* __restrict__ dinv,
    const int* __restrict__ start, const int* __restrict__ cnt,
    const int* __restrict__ csr, unsigned short* __restrict__ AGG,
    float* __restrict__ colsum, float* __restrict__ colsq, int n) {
    int tid = threadIdx.x;
    int wave = tid >> 6, lane = tid & 63;
    int g = lane >> 4, q = lane & 15;

    float s1[8], s2[8];
#pragma unroll
    for (int j = 0; j < 8; ++j) { s1[j] = 0.f; s2[j] = 0.f; }

    for (int i = blockIdx.x * 4 + wave; i < n; i += gridDim.x * 4) {
        float di = dinv[i];
        int s0 = start[i];
        int c = cnt[i];
        float acc[8];
#pragma unroll
        for (int j = 0; j < 8; ++j) acc[j] = 0.f;

        for (int t = g; t <= c; t += 4) {
            int s = (t == 0) ? i : csr[s0 + t - 1];
            float ds = dinv[s];
            uint4 hv = *(const uint4*)&Hb[(size_t)s * 128 + q * 8];
            unsigned short hu[8]; *(uint4*)hu = hv;
#pragma unroll
            for (int j = 0; j < 8; ++j) acc[j] += b2f(hu[j]) * ds;
        }
        // reduce across the 4 groups (lanes xor 16, 32), then apply dinv[i]
#pragma unroll
        for (int j = 0; j < 8; ++j) {
            acc[j] += __shfl_xor(acc[j], 16, 64);
            acc[j] += __shfl_xor(acc[j], 32, 64);
            acc[j] *= di;
        }
        if (g == 0) {
            unsigned short ou[8];
#pragma unroll
            for (int j = 0; j < 8; ++j) {
                float v = acc[j];
                ou[j] = f2b(v);
                s1[j] += v; s2[j] += v * v;
            }
            *(uint4*)&AGG[(size_t)i * 128 + q * 8] = *(uint4*)ou;
        }
    }

    __shared__ float sh[4][256];
    if (g == 0) {
#pragma unroll
        for (int j = 0; j < 8; ++j) {
            sh[wave][q * 8 + j] = s1[j];
            sh[wave][128 + q * 8 + j] = s2[j];
        }
    }
    __syncthreads();
    if (tid < 128) {
        float a = sh[0][tid] + sh[1][tid] + sh[2][tid] + sh[3][tid];
        float b = sh[0][128 + tid] + sh[1][128 + tid] + sh[2][128 + tid] + sh[3][128 + tid];
        atomicAdd(&colsum[tid], a);
        atomicAdd(&colsq[tid], b);
    }
}

// ---------------- BN finalize ----------------
__global__ void bn_fin(const float* __restrict__ colsum, const float* __restrict__ colsq,
                       const unsigned short* __restrict__ g, const unsigned short* __restrict__ beta,
                       const int* __restrict__ flag,
                       float* __restrict__ scale, float* __restrict__ shift, float invn) {
    int f = threadIdx.x;
    if (f >= 128) return;
    float cs = colsum[f], cq = colsq[f];
    if (!finitef(cs) || !finitef(cq)) { scale[f] = 0.f; shift[f] = 150.f; return; }
    float gv, bv;
    if (flag[0]) { gv = b2f(g[f]);            bv = b2f(beta[f]); }
    else         { gv = ((const float*)g)[f]; bv = ((const float*)beta)[f]; }
    float mu = cs * invn;
    float var = cq * invn - mu * mu;
    var = var < 0.f ? 0.f : var;
    float rstd = rsqrtf(var + 1e-5f);
    float s = gv * rstd;
    scale[f] = s;
    shift[f] = bv - mu * s;
}

// ---------------- final BN+ReLU to fp32 d_out, 8 elems/thread ----------------
__global__ void bn_apply_f32(const unsigned short* __restrict__ AGG, const float* __restrict__ scale,
                             const float* __restrict__ shift, float* __restrict__ out, int nchunk) {
    int i = blockIdx.x * 256 + threadIdx.x;
    if (i >= nchunk) return;
    int base = i * 8;
    int f0 = base & 127;
    uint4 hv = *(const uint4*)&AGG[base];
    unsigned short hu[8]; *(uint4*)hu = hv;
    float o[8];
#pragma unroll
    for (int j = 0; j < 8; ++j) {
        float v = b2f(hu[j]) * scale[f0 + j] + shift[f0 + j];
        o[j] = v > 0.f ? v : 0.f;
    }
    *(float4*)&out[base] = *(float4*)&o[0];
    *(float4*)&out[base + 4] = *(float4*)&o[4];
}

// ---------------- launch ----------------
extern "C" void kernel_launch(void* const* d_in, const int* in_sizes, int n_in,
                              void* d_out, int out_size, void* d_ws, size_t ws_size,
                              hipStream_t stream) {
    const unsigned short* X0 = (const unsigned short*)d_in[0];
    const int* ei = (const int*)d_in[1];
    const unsigned short* W1 = (const unsigned short*)d_in[2];
    const unsigned short* W2 = (const unsigned short*)d_in[4];
    const unsigned short* g1 = (const unsigned short*)d_in[6];
    const unsigned short* be1 = (const unsigned short*)d_in[7];
    const unsigned short* g2 = (const unsigned short*)d_in[8];
    const unsigned short* be2 = (const unsigned short*)d_in[9];
    float* OUT = (float*)d_out;

    int N = in_sizes[0] / HDIM;
    int E = in_sizes[1] / 2;
    int total = N * HDIM;
    int applyb = (total + 255) / 256;

    bool ok = (n_in == 10) && (N > 0) && (in_sizes[0] == N * HDIM) && (E > 0)
           && (in_sizes[2] == HDIM * HDIM) && (in_sizes[4] == HDIM * HDIM)
           && (in_sizes[6] == HDIM) && (in_sizes[9] == HDIM) && (out_size == total);
    if (!ok) { fill_f32<<<applyb, 256, 0, stream>>>(OUT, total, -100.0f); return; }

    size_t need = (size_t)N * 16 + 1024 + 2048 + 16 + (size_t)E * 12
                + (size_t)total * 2 * 2 + (size_t)HDIM * HDIM * 2 * 2;
    if (ws_size < need) { fill_f32<<<applyb, 256, 0, stream>>>(OUT, total, -300.0f); return; }

    char* w = (char*)d_ws;
    int* cnt = (int*)w;       w += (size_t)N * 4;
    int* start = (int*)w;     w += (size_t)N * 4;
    int* cursor = (int*)w;    w += (size_t)N * 4;
    float* dinv = (float*)w;  w += (size_t)N * 4;
    int* bsum = (int*)w;      w += 1024;
    float* stats = (float*)w; w += 2048;            // colsum|colsq|scale|shift
    int* flags = (int*)w;     w += 16;
    int* s32 = (int*)w;       w += (size_t)E * 4;
    int* d32 = (int*)w;       w += (size_t)E * 4;
    int* csr = (int*)w;       w += (size_t)E * 4;
    unsigned short* Hb = (unsigned short*)w;  w += (size_t)total * 2;
    unsigned short* AGG = (unsigned short*)w; w += (size_t)total * 2;
    unsigned short* Wt1 = (unsigned short*)w; w += (size_t)HDIM * HDIM * 2;
    unsigned short* Wt2 = (unsigned short*)w; w += (size_t)HDIM * HDIM * 2;

    float* colsum = stats;
    float* colsq = stats + 128;
    float* scale = stats + 256;
    float* shift = stats + 384;

    int nb = (N + 255) / 256;
    int ebl = (E + 255) / 256;
    int gemmb = (N + 63) / 64;
    float invn = 1.0f / (float)N;

    // dtype detect + W normalize/transpose
    detect_k<<<1, 256, 0, stream>>>(X0, flags);
    norm_w_t<<<64, 256, 0, stream>>>(W1, Wt1, flags);
    norm_w_t<<<64, 256, 0, stream>>>(W2, Wt2, flags);

    // graph structure
    zero_i32<<<nb, 256, 0, stream>>>(cnt, N);
    zero_i32<<<1, 256, 0, stream>>>((int*)stats, 256);
    edges_norm<<<ebl, 256, 0, stream>>>(ei, s32, d32, cnt, E, N);   // + fused degree hist
    dinv_k<<<nb, 256, 0, stream>>>(cnt, dinv, N);
    scan1<<<nb, 256, 0, stream>>>(cnt, bsum, N);
    scan2<<<1, 256, 0, stream>>>(bsum, nb);
    scan3<<<nb, 256, 0, stream>>>(cnt, bsum, start, cursor, N);
    scatter_k<<<ebl, 256, 0, stream>>>(s32, d32, cursor, csr, E);

    // layer 1
    gemm_mfma<<<gemmb, 256, 0, stream>>>(X0, Wt1, Hb, flags, -1, scale, shift, N);
    agg_stats<<<2048, 256, 0, stream>>>(Hb, dinv, start, cnt, csr, AGG, colsum, colsq, N);
    bn_fin<<<1, 256, 0, stream>>>(colsum, colsq, g1, be1, flags, scale, shift, invn);
    zero_i32<<<1, 256, 0, stream>>>((int*)stats, 256);   // colsum/colsq only; scale/shift survive

    // layer 2: BN+ReLU fused into gemm staging (reads AGG + scale/shift)
    gemm_mfma<<<gemmb, 256, 0, stream>>>(AGG, Wt2, Hb, flags, 2, scale, shift, N);
    agg_stats<<<2048, 256, 0, stream>>>(Hb, dinv, start, cnt, csr, AGG, colsum, colsq, N);
    bn_fin<<<1, 256, 0, stream>>>(colsum, colsq, g2, be2, flags, scale, shift, invn);
    bn_apply_f32<<<(total / 8 + 255) / 256, 256, 0, stream>>>(AGG, scale, shift, OUT, total / 8);
}

// Round 7
// 397.441 us; speedup vs baseline: 1.7433x; 1.0149x over previous
//
#include <hip/hip_runtime.h>

// ---------------- bf16 helpers (raw ushort storage) ----------------
__device__ __forceinline__ float b2f(unsigned short u) {
    union { unsigned int i; float f; } x; x.i = ((unsigned int)u) << 16; return x.f;
}
__device__ __forceinline__ unsigned short f2b(float f) {
    union { float f; unsigned int i; } x; x.f = f;
    unsigned int r = x.i + 0x7fffu + ((x.i >> 16) & 1u);   // RNE
    return (unsigned short)(r >> 16);
}
__device__ __forceinline__ bool finitef(float x) {
    union { float f; unsigned int u; } c; c.f = x;
    return ((c.u >> 23) & 0xffu) != 0xffu;
}

typedef __attribute__((ext_vector_type(8))) __bf16 bf16x8;
typedef __attribute__((ext_vector_type(4))) float f32x4;

#define HDIM 128
#define LSTR 136   // LDS row stride (ushorts): 128+8 pad -> 2-way b128 conflicts only (free)

// ---------------- failure-path fill ----------------
__global__ void fill_f32(float* p, int n, float v) {
    int i = blockIdx.x * 256 + threadIdx.x;
    if (i < n) p[i] = v;
}

// detect input float width
__global__ void detect_k(const unsigned short* __restrict__ x, int* __restrict__ flag) {
    __shared__ int sane;
    int tid = threadIdx.x;
    if (tid == 0) sane = 0;
    __syncthreads();
    unsigned short u = x[2 * tid];
    int e = (u >> 7) & 0xff;
    if (e >= 100 && e <= 140) atomicAdd(&sane, 1);
    __syncthreads();
    if (tid == 0) flag[0] = (sane >= 128) ? 1 : 0;
}

// normalize BOTH weights to bf16 + transpose in one launch (grid = 128 blocks)
__global__ void norm_w_t2(const unsigned short* __restrict__ W1, const unsigned short* __restrict__ W2,
                          unsigned short* __restrict__ Wt1, unsigned short* __restrict__ Wt2,
                          const int* __restrict__ flag) {
    int idx = blockIdx.x * 256 + threadIdx.x;   // 0..32767
    const unsigned short* src;
    unsigned short* dst;
    int l;
    if (idx < 16384) { src = W1; dst = Wt1; l = idx; }
    else             { src = W2; dst = Wt2; l = idx - 16384; }
    int k = l >> 7, c = l & 127;
    unsigned short v = flag[0] ? src[l] : f2b(((const float*)src)[l]);
    dst[c * 128 + k] = v;   // Wt[n][k]
}

__global__ void zero_i32(int* p, int n) {
    int i = blockIdx.x * 256 + threadIdx.x;
    if (i < n) p[i] = 0;
}

// ---------------- edges: dtype detect, compact, clamp, fused degree histogram ----------------
__global__ void edges_norm(const int* __restrict__ ei, int* __restrict__ s32,
                           int* __restrict__ d32, int* __restrict__ cnt, int E, int N) {
    __shared__ int sh;
    if (threadIdx.x == 0) {
        int acc = 0;
        for (int k = 1; k < 129; k += 2) acc |= ei[k];  // int64 => high words all 0
        sh = (acc == 0) ? 1 : 0;
    }
    __syncthreads();
    int is64 = sh;
    int e = blockIdx.x * 256 + threadIdx.x;
    if (e < E) {
        int s, d;
        if (is64) { s = ei[2 * (size_t)e]; d = ei[2 * (size_t)E + 2 * (size_t)e]; }
        else      { s = ei[e];             d = ei[(size_t)E + e]; }
        s = s < 0 ? 0 : (s >= N ? N - 1 : s);
        d = d < 0 ? 0 : (d >= N ? N - 1 : d);
        s32[e] = s; d32[e] = d;
        atomicAdd(&cnt[d], 1);
    }
}

// ---------------- scan (block sums) + fused dinv ----------------
__global__ void scan1(const int* __restrict__ cnt, int* __restrict__ bsum,
                      float* __restrict__ dinv, int n) {
    __shared__ int sh[256];
    int t = threadIdx.x;
    int i = blockIdx.x * 256 + t;
    int v = (i < n) ? cnt[i] : 0;
    sh[t] = v;
    if (i < n) dinv[i] = rsqrtf((float)v + 1.0f);   // +1 self-loop
    __syncthreads();
    for (int s = 128; s > 0; s >>= 1) {
        if (t < s) sh[t] += sh[t + s];
        __syncthreads();
    }
    if (t == 0) bsum[blockIdx.x] = sh[0];
}

__global__ void scan2(int* bsum, int nblk) {
    __shared__ int sh[256];
    int t = threadIdx.x;
    sh[t] = (t < nblk) ? bsum[t] : 0;
    __syncthreads();
    for (int off = 1; off < 256; off <<= 1) {
        int v = (t >= off) ? sh[t - off] : 0;
        __syncthreads();
        sh[t] += v;
        __syncthreads();
    }
    if (t < nblk) bsum[t] = (t == 0) ? 0 : sh[t - 1];
}

// writes per-node meta {start, cnt, dinv_bits} (single int4 load in agg) + cursor
__global__ void scan3(const int* __restrict__ cnt, const int* __restrict__ bsum,
                      int4* __restrict__ meta, int* __restrict__ cursor, int n) {
    __shared__ int sh[256];
    int t = threadIdx.x;
    int i = blockIdx.x * 256 + t;
    int v = (i < n) ? cnt[i] : 0;
    sh[t] = v;
    __syncthreads();
    for (int off = 1; off < 256; off <<= 1) {
        int a = (t >= off) ? sh[t - off] : 0;
        __syncthreads();
        sh[t] += a;
        __syncthreads();
    }
    if (i < n) {
        int excl = sh[t] - v + bsum[blockIdx.x];
        float dv = rsqrtf((float)v + 1.0f);
        meta[i] = make_int4(excl, v, __float_as_int(dv), 0);
        cursor[i] = excl;
    }
}

__global__ void scatter_k(const int* __restrict__ s32, const int* __restrict__ d32,
                          int* __restrict__ cursor, int* __restrict__ csr, int E) {
    int e = blockIdx.x * 256 + threadIdx.x;
    if (e < E) {
        int slot = atomicAdd(&cursor[d32[e]], 1);
        csr[slot] = s32[e];
    }
}

// ---------------- GEMM (MFMA 16x16x32 bf16): C[n,128] = A[n,128] @ W ----------------
__global__ __launch_bounds__(256) void gemm_mfma(
    const unsigned short* __restrict__ A, const unsigned short* __restrict__ Wt,
    unsigned short* __restrict__ C, const int* __restrict__ aflag, int mode,
    const float* __restrict__ scale, const float* __restrict__ shift, int n) {
    __shared__ __align__(16) unsigned short Wl[128 * LSTR];
    __shared__ __align__(16) unsigned short Al[64 * LSTR];
    int tid = threadIdx.x;
    int row0 = blockIdx.x * 64;

    const uint4* Wg = (const uint4*)Wt;
#pragma unroll
    for (int it = 0; it < 8; ++it) {
        int idx = tid + it * 256;
        int nn = idx >> 4, k8 = idx & 15;
        *(uint4*)&Wl[nn * LSTR + k8 * 8] = Wg[idx];
    }

    int amode = (mode == 2) ? 2 : aflag[0];
    if (amode == 1) {
        const uint4* Ag = (const uint4*)A;
        for (int it = 0; it < 4; ++it) {
            int idx = tid + it * 256;
            int r = idx >> 4, cc = idx & 15;
            int gr = row0 + r;
            uint4 v; v.x = v.y = v.z = v.w = 0u;
            if (gr < n) v = Ag[(size_t)gr * 16 + cc];
            *(uint4*)&Al[r * LSTR + cc * 8] = v;
        }
    } else if (amode == 0) {
        const uint4* Af = (const uint4*)A;
        for (int it = 0; it < 8; ++it) {
            int idx = tid + it * 256;
            int r = idx >> 5, c4 = idx & 31;
            int gr = row0 + r;
            uint4 v; v.x = v.y = v.z = v.w = 0u;
            if (gr < n) v = Af[(size_t)gr * 32 + c4];
            float ff[4]; *(uint4*)ff = v;
            ushort4 o;
            o.x = f2b(ff[0]); o.y = f2b(ff[1]); o.z = f2b(ff[2]); o.w = f2b(ff[3]);
            *(ushort4*)&Al[r * LSTR + c4 * 4] = o;
        }
    } else {                   // AGG bf16 + fused BN + ReLU
        const uint4* Ag = (const uint4*)A;
        for (int it = 0; it < 4; ++it) {
            int idx = tid + it * 256;
            int r = idx >> 4, cc = idx & 15;
            int gr = row0 + r;
            uint4 v; v.x = v.y = v.z = v.w = 0u;
            if (gr < n) v = Ag[(size_t)gr * 16 + cc];
            unsigned short hu[8]; *(uint4*)hu = v;
            unsigned short ou[8];
#pragma unroll
            for (int j = 0; j < 8; ++j) {
                int f = cc * 8 + j;
                float x = b2f(hu[j]) * scale[f] + shift[f];
                ou[j] = f2b(x > 0.f ? x : 0.f);
            }
            *(uint4*)&Al[r * LSTR + cc * 8] = *(uint4*)ou;
        }
    }
    __syncthreads();

    int wave = tid >> 6, lane = tid & 63;
    int m = lane & 15, quad = lane >> 4;

    bf16x8 afr[4];
#pragma unroll
    for (int kc = 0; kc < 4; ++kc)
        afr[kc] = *(const bf16x8*)&Al[(wave * 16 + m) * LSTR + kc * 32 + quad * 8];

    for (int t = 0; t < 8; ++t) {
        f32x4 acc = {0.f, 0.f, 0.f, 0.f};
#pragma unroll
        for (int kc = 0; kc < 4; ++kc) {
            bf16x8 bfr = *(const bf16x8*)&Wl[(t * 16 + m) * LSTR + kc * 32 + quad * 8];
            acc = __builtin_amdgcn_mfma_f32_16x16x32_bf16(afr[kc], bfr, acc, 0, 0, 0);
        }
#pragma unroll
        for (int i2 = 0; i2 < 4; ++i2) {
            int gr = row0 + wave * 16 + quad * 4 + i2;
            if (gr < n) C[(size_t)gr * 128 + t * 16 + m] = f2b(acc[i2]);
        }
    }
}

// ---------------- aggregation + fused BN column stats ----------------
// 1 wave/node (grid-stride); 4 groups x 16 lanes; lane gathers uint4 (8 bf16).
// Self-loop hoisted to group 0; edge loop unrolled x2 for 2 gather chains in flight.
__global__ __launch_bounds__(256) void agg_stats(
    const unsigned short* __restrict__ Hb, const float* __restrict__ dinv,
    const int4* __restrict__ meta, const int* __restrict__ csr,
    unsigned short* __restrict__ AGG,
    float* __restrict__ colsum, float* __restrict__ colsq, int n) {
    int tid = threadIdx.x;
    int wave = tid >> 6, lane = tid & 63;
    int g = lane >> 4, q = lane & 15;

    float s1[8], s2[8];
#pragma unroll
    for (int j = 0; j < 8; ++j) { s1[j] = 0.f; s2[j] = 0.f; }

    for (int i = blockIdx.x * 4 + wave; i < n; i += gridDim.x * 4) {
        int4 mt = meta[i];                       // {start, cnt, dinv_bits}
        int s0 = mt.x, c = mt.y;
        float di = __int_as_float(mt.z);
        float acc[8];
#pragma unroll
        for (int j = 0; j < 8; ++j) acc[j] = 0.f;

        if (g == 0) {   // self-loop
            uint4 a4 = *(const uint4*)&Hb[(size_t)i * 128 + q * 8];
            unsigned short au[8]; *(uint4*)au = a4;
#pragma unroll
            for (int j = 0; j < 8; ++j) acc[j] += b2f(au[j]) * di;
        }

        int t = g;
        for (; t + 4 < c; t += 8) {              // two independent gather chains
            int sA = csr[s0 + t];
            int sB = csr[s0 + t + 4];
            float dA = dinv[sA];
            float dB = dinv[sB];
            uint4 a4 = *(const uint4*)&Hb[(size_t)sA * 128 + q * 8];
            uint4 b4 = *(const uint4*)&Hb[(size_t)sB * 128 + q * 8];
            unsigned short au[8]; *(uint4*)au = a4;
            unsigned short bu[8]; *(uint4*)bu = b4;
#pragma unroll
            for (int j = 0; j < 8; ++j) acc[j] += b2f(au[j]) * dA + b2f(bu[j]) * dB;
        }
        if (t < c) {
            int sA = csr[s0 + t];
            float dA = dinv[sA];
            uint4 a4 = *(const uint4*)&Hb[(size_t)sA * 128 + q * 8];
            unsigned short au[8]; *(uint4*)au = a4;
#pragma unroll
            for (int j = 0; j < 8; ++j) acc[j] += b2f(au[j]) * dA;
        }

#pragma unroll
        for (int j = 0; j < 8; ++j) {
            acc[j] += __shfl_xor(acc[j], 16, 64);
            acc[j] += __shfl_xor(acc[j], 32, 64);
            acc[j] *= di;
        }
        if (g == 0) {
            unsigned short ou[8];
#pragma unroll
            for (int j = 0; j < 8; ++j) {
                float v = acc[j];
                ou[j] = f2b(v);
                s1[j] += v; s2[j] += v * v;
            }
            *(uint4*)&AGG[(size_t)i * 128 + q * 8] = *(uint4*)ou;
        }
    }

    __shared__ float sh[4][256];
    if (g == 0) {
#pragma unroll
        for (int j = 0; j < 8; ++j) {
            sh[wave][q * 8 + j] = s1[j];
            sh[wave][128 + q * 8 + j] = s2[j];
        }
    }
    __syncthreads();
    if (tid < 128) {
        float a = sh[0][tid] + sh[1][tid] + sh[2][tid] + sh[3][tid];
        float b = sh[0][128 + tid] + sh[1][128 + tid] + sh[2][128 + tid] + sh[3][128 + tid];
        atomicAdd(&colsum[tid], a);
        atomicAdd(&colsq[tid], b);
    }
}

// ---------------- BN finalize (self-zeroes stats for next layer) ----------------
__global__ void bn_fin(float* __restrict__ colsum, float* __restrict__ colsq,
                       const unsigned short* __restrict__ g, const unsigned short* __restrict__ beta,
                       const int* __restrict__ flag,
                       float* __restrict__ scale, float* __restrict__ shift, float invn) {
    int f = threadIdx.x;
    if (f >= 128) return;
    float cs = colsum[f], cq = colsq[f];
    colsum[f] = 0.f; colsq[f] = 0.f;             // ready for next layer
    if (!finitef(cs) || !finitef(cq)) { scale[f] = 0.f; shift[f] = 150.f; return; }
    float gv, bv;
    if (flag[0]) { gv = b2f(g[f]);            bv = b2f(beta[f]); }
    else         { gv = ((const float*)g)[f]; bv = ((const float*)beta)[f]; }
    float mu = cs * invn;
    float var = cq * invn - mu * mu;
    var = var < 0.f ? 0.f : var;
    float rstd = rsqrtf(var + 1e-5f);
    float s = gv * rstd;
    scale[f] = s;
    shift[f] = bv - mu * s;
}

// ---------------- final BN+ReLU to fp32 d_out, 8 elems/thread ----------------
__global__ void bn_apply_f32(const unsigned short* __restrict__ AGG, const float* __restrict__ scale,
                             const float* __restrict__ shift, float* __restrict__ out, int nchunk) {
    int i = blockIdx.x * 256 + threadIdx.x;
    if (i >= nchunk) return;
    int base = i * 8;
    int f0 = base & 127;
    uint4 hv = *(const uint4*)&AGG[base];
    unsigned short hu[8]; *(uint4*)hu = hv;
    float o[8];
#pragma unroll
    for (int j = 0; j < 8; ++j) {
        float v = b2f(hu[j]) * scale[f0 + j] + shift[f0 + j];
        o[j] = v > 0.f ? v : 0.f;
    }
    *(float4*)&out[base] = *(float4*)&o[0];
    *(float4*)&out[base + 4] = *(float4*)&o[4];
}

// ---------------- launch ----------------
extern "C" void kernel_launch(void* const* d_in, const int* in_sizes, int n_in,
                              void* d_out, int out_size, void* d_ws, size_t ws_size,
                              hipStream_t stream) {
    const unsigned short* X0 = (const unsigned short*)d_in[0];
    const int* ei = (const int*)d_in[1];
    const unsigned short* W1 = (const unsigned short*)d_in[2];
    const unsigned short* W2 = (const unsigned short*)d_in[4];
    const unsigned short* g1 = (const unsigned short*)d_in[6];
    const unsigned short* be1 = (const unsigned short*)d_in[7];
    const unsigned short* g2 = (const unsigned short*)d_in[8];
    const unsigned short* be2 = (const unsigned short*)d_in[9];
    float* OUT = (float*)d_out;

    int N = in_sizes[0] / HDIM;
    int E = in_sizes[1] / 2;
    int total = N * HDIM;
    int applyb = (total + 255) / 256;

    bool ok = (n_in == 10) && (N > 0) && (in_sizes[0] == N * HDIM) && (E > 0)
           && (in_sizes[2] == HDIM * HDIM) && (in_sizes[4] == HDIM * HDIM)
           && (in_sizes[6] == HDIM) && (in_sizes[9] == HDIM) && (out_size == total);
    if (!ok) { fill_f32<<<applyb, 256, 0, stream>>>(OUT, total, -100.0f); return; }

    size_t need = (size_t)N * 28 + 2048 + 16 + 1024 + (size_t)E * 12
                + (size_t)total * 4 + 65536 + 1024;
    if (ws_size < need) { fill_f32<<<applyb, 256, 0, stream>>>(OUT, total, -300.0f); return; }

    char* w = (char*)d_ws;
    int* cnt = (int*)w;       w += (size_t)N * 4;       // [zero region start]
    float* stats = (float*)w; w += 2048;                // colsum|colsq|scale|shift (512 f)
    int* flags = (int*)w;     w += 16;
    int* bsum = (int*)w;      w += 1024;
    float* dinv = (float*)w;  w += (size_t)N * 4;
    int* cursor = (int*)w;    w += (size_t)N * 4;
    w = (char*)(((uintptr_t)w + 15) & ~(uintptr_t)15);
    int4* meta = (int4*)w;    w += (size_t)N * 16;
    int* s32 = (int*)w;       w += (size_t)E * 4;
    int* d32 = (int*)w;       w += (size_t)E * 4;
    int* csr = (int*)w;       w += (size_t)E * 4;
    unsigned short* Hb = (unsigned short*)w;  w += (size_t)total * 2;
    unsigned short* AGG = (unsigned short*)w; w += (size_t)total * 2;
    unsigned short* Wt1 = (unsigned short*)w; w += (size_t)HDIM * HDIM * 2;
    unsigned short* Wt2 = (unsigned short*)w; w += (size_t)HDIM * HDIM * 2;

    float* colsum = stats;
    float* colsq = stats + 128;
    float* scale = stats + 256;
    float* shift = stats + 384;

    int nb = (N + 255) / 256;
    int ebl = (E + 255) / 256;
    int gemmb = (N + 63) / 64;
    float invn = 1.0f / (float)N;

    detect_k<<<1, 256, 0, stream>>>(X0, flags);
    norm_w_t2<<<128, 256, 0, stream>>>(W1, W2, Wt1, Wt2, flags);
    zero_i32<<<(N + 512 + 255) / 256, 256, 0, stream>>>(cnt, N + 512);  // cnt + colsum/colsq (+scale/shift harmless)

    edges_norm<<<ebl, 256, 0, stream>>>(ei, s32, d32, cnt, E, N);
    scan1<<<nb, 256, 0, stream>>>(cnt, bsum, dinv, N);
    scan2<<<1, 256, 0, stream>>>(bsum, nb);
    scan3<<<nb, 256, 0, stream>>>(cnt, bsum, meta, cursor, N);
    scatter_k<<<ebl, 256, 0, stream>>>(s32, d32, cursor, csr, E);

    // layer 1
    gemm_mfma<<<gemmb, 256, 0, stream>>>(X0, Wt1, Hb, flags, -1, scale, shift, N);
    agg_stats<<<2048, 256, 0, stream>>>(Hb, dinv, meta, csr, AGG, colsum, colsq, N);
    bn_fin<<<1, 256, 0, stream>>>(colsum, colsq, g1, be1, flags, scale, shift, invn);

    // layer 2 (BN+ReLU fused into gemm A-staging)
    gemm_mfma<<<gemmb, 256, 0, stream>>>(AGG, Wt2, Hb, flags, 2, scale, shift, N);
    agg_stats<<<2048, 256, 0, stream>>>(Hb, dinv, meta, csr, AGG, colsum, colsq, N);
    bn_fin<<<1, 256, 0, stream>>>(colsum, colsq, g2, be2, flags, scale, shift, invn);
    bn_apply_f32<<<(total / 8 + 255) / 256, 256, 0, stream>>>(AGG, scale, shift, OUT, total / 8);
}

// Round 8
// 384.315 us; speedup vs baseline: 1.8029x; 1.0342x over previous
//
#include <hip/hip_runtime.h>

// ---------------- bf16 helpers (raw ushort storage) ----------------
__device__ __forceinline__ float b2f(unsigned short u) {
    union { unsigned int i; float f; } x; x.i = ((unsigned int)u) << 16; return x.f;
}
__device__ __forceinline__ unsigned short f2b(float f) {
    union { float f; unsigned int i; } x; x.f = f;
    unsigned int r = x.i + 0x7fffu + ((x.i >> 16) & 1u);   // RNE
    return (unsigned short)(r >> 16);
}
__device__ __forceinline__ bool finitef(float x) {
    union { float f; unsigned int u; } c; c.f = x;
    return ((c.u >> 23) & 0xffu) != 0xffu;
}

typedef __attribute__((ext_vector_type(8))) __bf16 bf16x8;
typedef __attribute__((ext_vector_type(4))) float f32x4;

#define HDIM 128
#define LSTR 136   // LDS row stride (ushorts): 128+8 pad -> 2-way b128 conflicts only (free)

// ---------------- failure-path fill ----------------
__global__ void fill_f32(float* p, int n, float v) {
    int i = blockIdx.x * 256 + threadIdx.x;
    if (i < n) p[i] = v;
}

// detect input float width
__global__ void detect_k(const unsigned short* __restrict__ x, int* __restrict__ flag) {
    __shared__ int sane;
    int tid = threadIdx.x;
    if (tid == 0) sane = 0;
    __syncthreads();
    unsigned short u = x[2 * tid];
    int e = (u >> 7) & 0xff;
    if (e >= 100 && e <= 140) atomicAdd(&sane, 1);
    __syncthreads();
    if (tid == 0) flag[0] = (sane >= 128) ? 1 : 0;
}

// normalize BOTH weights to bf16 + transpose in one launch (grid = 128 blocks)
__global__ void norm_w_t2(const unsigned short* __restrict__ W1, const unsigned short* __restrict__ W2,
                          unsigned short* __restrict__ Wt1, unsigned short* __restrict__ Wt2,
                          const int* __restrict__ flag) {
    int idx = blockIdx.x * 256 + threadIdx.x;   // 0..32767
    const unsigned short* src;
    unsigned short* dst;
    int l;
    if (idx < 16384) { src = W1; dst = Wt1; l = idx; }
    else             { src = W2; dst = Wt2; l = idx - 16384; }
    int k = l >> 7, c = l & 127;
    unsigned short v = flag[0] ? src[l] : f2b(((const float*)src)[l]);
    dst[c * 128 + k] = v;   // Wt[n][k]
}

__global__ void zero_i32(int* p, int n) {
    int i = blockIdx.x * 256 + threadIdx.x;
    if (i < n) p[i] = 0;
}

// ---------------- edges: dtype detect, compact, clamp, fused degree histogram ----------------
__global__ void edges_norm(const int* __restrict__ ei, int* __restrict__ s32,
                           int* __restrict__ d32, int* __restrict__ cnt, int E, int N) {
    __shared__ int sh;
    if (threadIdx.x == 0) {
        int acc = 0;
        for (int k = 1; k < 129; k += 2) acc |= ei[k];  // int64 => high words all 0
        sh = (acc == 0) ? 1 : 0;
    }
    __syncthreads();
    int is64 = sh;
    int e = blockIdx.x * 256 + threadIdx.x;
    if (e < E) {
        int s, d;
        if (is64) { s = ei[2 * (size_t)e]; d = ei[2 * (size_t)E + 2 * (size_t)e]; }
        else      { s = ei[e];             d = ei[(size_t)E + e]; }
        s = s < 0 ? 0 : (s >= N ? N - 1 : s);
        d = d < 0 ? 0 : (d >= N ? N - 1 : d);
        s32[e] = s; d32[e] = d;
        atomicAdd(&cnt[d], 1);
    }
}

// ---------------- scan (block sums) + fused dinv ----------------
__global__ void scan1(const int* __restrict__ cnt, int* __restrict__ bsum,
                      float* __restrict__ dinv, int n) {
    __shared__ int sh[256];
    int t = threadIdx.x;
    int i = blockIdx.x * 256 + t;
    int v = (i < n) ? cnt[i] : 0;
    sh[t] = v;
    if (i < n) dinv[i] = rsqrtf((float)v + 1.0f);   // +1 self-loop
    __syncthreads();
    for (int s = 128; s > 0; s >>= 1) {
        if (t < s) sh[t] += sh[t + s];
        __syncthreads();
    }
    if (t == 0) bsum[blockIdx.x] = sh[0];
}

__global__ void scan2(int* bsum, int nblk) {
    __shared__ int sh[256];
    int t = threadIdx.x;
    sh[t] = (t < nblk) ? bsum[t] : 0;
    __syncthreads();
    for (int off = 1; off < 256; off <<= 1) {
        int v = (t >= off) ? sh[t - off] : 0;
        __syncthreads();
        sh[t] += v;
        __syncthreads();
    }
    if (t < nblk) bsum[t] = (t == 0) ? 0 : sh[t - 1];
}

// writes per-node meta {start, cnt, dinv_bits} + cursor
__global__ void scan3(const int* __restrict__ cnt, const int* __restrict__ bsum,
                      int4* __restrict__ meta, int* __restrict__ cursor, int n) {
    __shared__ int sh[256];
    int t = threadIdx.x;
    int i = blockIdx.x * 256 + t;
    int v = (i < n) ? cnt[i] : 0;
    sh[t] = v;
    __syncthreads();
    for (int off = 1; off < 256; off <<= 1) {
        int a = (t >= off) ? sh[t - off] : 0;
        __syncthreads();
        sh[t] += a;
        __syncthreads();
    }
    if (i < n) {
        int excl = sh[t] - v + bsum[blockIdx.x];
        float dv = rsqrtf((float)v + 1.0f);
        meta[i] = make_int4(excl, v, __float_as_int(dv), 0);
        cursor[i] = excl;
    }
}

__global__ void scatter_k(const int* __restrict__ s32, const int* __restrict__ d32,
                          int* __restrict__ cursor, int* __restrict__ csr, int E) {
    int e = blockIdx.x * 256 + threadIdx.x;
    if (e < E) {
        int slot = atomicAdd(&cursor[d32[e]], 1);
        csr[slot] = s32[e];
    }
}

// ---------------- GEMM (MFMA 16x16x32 bf16): C[n,128] = dinv[n] * (A[n,128] @ W) ----------------
// Epilogue pre-scales rows by dinv so the aggregation needs NO per-edge dinv gather.
__global__ __launch_bounds__(256) void gemm_mfma(
    const unsigned short* __restrict__ A, const unsigned short* __restrict__ Wt,
    unsigned short* __restrict__ C, const int* __restrict__ aflag, int mode,
    const float* __restrict__ scale, const float* __restrict__ shift,
    const float* __restrict__ dinv, int n) {
    __shared__ __align__(16) unsigned short Wl[128 * LSTR];
    __shared__ __align__(16) unsigned short Al[64 * LSTR];
    int tid = threadIdx.x;
    int row0 = blockIdx.x * 64;

    const uint4* Wg = (const uint4*)Wt;
#pragma unroll
    for (int it = 0; it < 8; ++it) {
        int idx = tid + it * 256;
        int nn = idx >> 4, k8 = idx & 15;
        *(uint4*)&Wl[nn * LSTR + k8 * 8] = Wg[idx];
    }

    int amode = (mode == 2) ? 2 : aflag[0];
    if (amode == 1) {
        const uint4* Ag = (const uint4*)A;
        for (int it = 0; it < 4; ++it) {
            int idx = tid + it * 256;
            int r = idx >> 4, cc = idx & 15;
            int gr = row0 + r;
            uint4 v; v.x = v.y = v.z = v.w = 0u;
            if (gr < n) v = Ag[(size_t)gr * 16 + cc];
            *(uint4*)&Al[r * LSTR + cc * 8] = v;
        }
    } else if (amode == 0) {
        const uint4* Af = (const uint4*)A;
        for (int it = 0; it < 8; ++it) {
            int idx = tid + it * 256;
            int r = idx >> 5, c4 = idx & 31;
            int gr = row0 + r;
            uint4 v; v.x = v.y = v.z = v.w = 0u;
            if (gr < n) v = Af[(size_t)gr * 32 + c4];
            float ff[4]; *(uint4*)ff = v;
            ushort4 o;
            o.x = f2b(ff[0]); o.y = f2b(ff[1]); o.z = f2b(ff[2]); o.w = f2b(ff[3]);
            *(ushort4*)&Al[r * LSTR + c4 * 4] = o;
        }
    } else {                   // AGG bf16 + fused BN + ReLU
        const uint4* Ag = (const uint4*)A;
        for (int it = 0; it < 4; ++it) {
            int idx = tid + it * 256;
            int r = idx >> 4, cc = idx & 15;
            int gr = row0 + r;
            uint4 v; v.x = v.y = v.z = v.w = 0u;
            if (gr < n) v = Ag[(size_t)gr * 16 + cc];
            unsigned short hu[8]; *(uint4*)hu = v;
            unsigned short ou[8];
#pragma unroll
            for (int j = 0; j < 8; ++j) {
                int f = cc * 8 + j;
                float x = b2f(hu[j]) * scale[f] + shift[f];
                ou[j] = f2b(x > 0.f ? x : 0.f);
            }
            *(uint4*)&Al[r * LSTR + cc * 8] = *(uint4*)ou;
        }
    }
    __syncthreads();

    int wave = tid >> 6, lane = tid & 63;
    int m = lane & 15, quad = lane >> 4;

    bf16x8 afr[4];
#pragma unroll
    for (int kc = 0; kc < 4; ++kc)
        afr[kc] = *(const bf16x8*)&Al[(wave * 16 + m) * LSTR + kc * 32 + quad * 8];

    // per-lane output rows are fixed across t-tiles: load their dinv once
    float dv[4];
#pragma unroll
    for (int i2 = 0; i2 < 4; ++i2) {
        int gr = row0 + wave * 16 + quad * 4 + i2;
        dv[i2] = (gr < n) ? dinv[gr] : 0.f;
    }

    for (int t = 0; t < 8; ++t) {
        f32x4 acc = {0.f, 0.f, 0.f, 0.f};
#pragma unroll
        for (int kc = 0; kc < 4; ++kc) {
            bf16x8 bfr = *(const bf16x8*)&Wl[(t * 16 + m) * LSTR + kc * 32 + quad * 8];
            acc = __builtin_amdgcn_mfma_f32_16x16x32_bf16(afr[kc], bfr, acc, 0, 0, 0);
        }
#pragma unroll
        for (int i2 = 0; i2 < 4; ++i2) {
            int gr = row0 + wave * 16 + quad * 4 + i2;
            if (gr < n) C[(size_t)gr * 128 + t * 16 + m] = f2b(acc[i2] * dv[i2]);
        }
    }
}

// ---------------- aggregation + fused BN column stats ----------------
// Hb rows are PRE-SCALED by dinv[src]: out[i] = dinv[i] * (Hb[i] + sum Hb[csr]).
// 1 wave/node; 4 groups x 16 lanes; lane gathers uint4 (8 bf16). Unroll x4:
// 4 csr index loads issued up-front, then 4 independent row gathers in flight.
__global__ __launch_bounds__(256) void agg_stats(
    const unsigned short* __restrict__ Hb,
    const int4* __restrict__ meta, const int* __restrict__ csr,
    unsigned short* __restrict__ AGG,
    float* __restrict__ colsum, float* __restrict__ colsq, int n) {
    int tid = threadIdx.x;
    int wave = tid >> 6, lane = tid & 63;
    int g = lane >> 4, q = lane & 15;

    float s1[8], s2[8];
#pragma unroll
    for (int j = 0; j < 8; ++j) { s1[j] = 0.f; s2[j] = 0.f; }

    for (int i = blockIdx.x * 4 + wave; i < n; i += gridDim.x * 4) {
        int4 mt = meta[i];                       // {start, cnt, dinv_bits}
        int s0 = mt.x, c = mt.y;
        float di = __int_as_float(mt.z);
        float acc[8];
#pragma unroll
        for (int j = 0; j < 8; ++j) acc[j] = 0.f;

        if (g == 0) {   // self-loop (pre-scaled row)
            uint4 a4 = *(const uint4*)&Hb[(size_t)i * 128 + q * 8];
            unsigned short au[8]; *(uint4*)au = a4;
#pragma unroll
            for (int j = 0; j < 8; ++j) acc[j] += b2f(au[j]);
        }

        int t = g;
        for (; t + 12 < c; t += 16) {            // 4 independent gather chains
            int sA = csr[s0 + t];
            int sB = csr[s0 + t + 4];
            int sC = csr[s0 + t + 8];
            int sD = csr[s0 + t + 12];
            uint4 a4 = *(const uint4*)&Hb[(size_t)sA * 128 + q * 8];
            uint4 b4 = *(const uint4*)&Hb[(size_t)sB * 128 + q * 8];
            uint4 c4 = *(const uint4*)&Hb[(size_t)sC * 128 + q * 8];
            uint4 d4 = *(const uint4*)&Hb[(size_t)sD * 128 + q * 8];
            unsigned short au[8]; *(uint4*)au = a4;
            unsigned short bu[8]; *(uint4*)bu = b4;
            unsigned short cu[8]; *(uint4*)cu = c4;
            unsigned short du[8]; *(uint4*)du = d4;
#pragma unroll
            for (int j = 0; j < 8; ++j)
                acc[j] += (b2f(au[j]) + b2f(bu[j])) + (b2f(cu[j]) + b2f(du[j]));
        }
        for (; t < c; t += 4) {
            int sA = csr[s0 + t];
            uint4 a4 = *(const uint4*)&Hb[(size_t)sA * 128 + q * 8];
            unsigned short au[8]; *(uint4*)au = a4;
#pragma unroll
            for (int j = 0; j < 8; ++j) acc[j] += b2f(au[j]);
        }

#pragma unroll
        for (int j = 0; j < 8; ++j) {
            acc[j] += __shfl_xor(acc[j], 16, 64);
            acc[j] += __shfl_xor(acc[j], 32, 64);
            acc[j] *= di;
        }
        if (g == 0) {
            unsigned short ou[8];
#pragma unroll
            for (int j = 0; j < 8; ++j) {
                float v = acc[j];
                ou[j] = f2b(v);
                s1[j] += v; s2[j] += v * v;
            }
            *(uint4*)&AGG[(size_t)i * 128 + q * 8] = *(uint4*)ou;
        }
    }

    __shared__ float sh[4][256];
    if (g == 0) {
#pragma unroll
        for (int j = 0; j < 8; ++j) {
            sh[wave][q * 8 + j] = s1[j];
            sh[wave][128 + q * 8 + j] = s2[j];
        }
    }
    __syncthreads();
    if (tid < 128) {
        float a = sh[0][tid] + sh[1][tid] + sh[2][tid] + sh[3][tid];
        float b = sh[0][128 + tid] + sh[1][128 + tid] + sh[2][128 + tid] + sh[3][128 + tid];
        atomicAdd(&colsum[tid], a);
        atomicAdd(&colsq[tid], b);
    }
}

// ---------------- BN finalize (self-zeroes stats for next layer) ----------------
__global__ void bn_fin(float* __restrict__ colsum, float* __restrict__ colsq,
                       const unsigned short* __restrict__ g, const unsigned short* __restrict__ beta,
                       const int* __restrict__ flag,
                       float* __restrict__ scale, float* __restrict__ shift, float invn) {
    int f = threadIdx.x;
    if (f >= 128) return;
    float cs = colsum[f], cq = colsq[f];
    colsum[f] = 0.f; colsq[f] = 0.f;
    if (!finitef(cs) || !finitef(cq)) { scale[f] = 0.f; shift[f] = 150.f; return; }
    float gv, bv;
    if (flag[0]) { gv = b2f(g[f]);            bv = b2f(beta[f]); }
    else         { gv = ((const float*)g)[f]; bv = ((const float*)beta)[f]; }
    float mu = cs * invn;
    float var = cq * invn - mu * mu;
    var = var < 0.f ? 0.f : var;
    float rstd = rsqrtf(var + 1e-5f);
    float s = gv * rstd;
    scale[f] = s;
    shift[f] = bv - mu * s;
}

// ---------------- final BN+ReLU to fp32 d_out, 8 elems/thread ----------------
__global__ void bn_apply_f32(const unsigned short* __restrict__ AGG, const float* __restrict__ scale,
                             const float* __restrict__ shift, float* __restrict__ out, int nchunk) {
    int i = blockIdx.x * 256 + threadIdx.x;
    if (i >= nchunk) return;
    int base = i * 8;
    int f0 = base & 127;
    uint4 hv = *(const uint4*)&AGG[base];
    unsigned short hu[8]; *(uint4*)hu = hv;
    float o[8];
#pragma unroll
    for (int j = 0; j < 8; ++j) {
        float v = b2f(hu[j]) * scale[f0 + j] + shift[f0 + j];
        o[j] = v > 0.f ? v : 0.f;
    }
    *(float4*)&out[base] = *(float4*)&o[0];
    *(float4*)&out[base + 4] = *(float4*)&o[4];
}

// ---------------- launch ----------------
extern "C" void kernel_launch(void* const* d_in, const int* in_sizes, int n_in,
                              void* d_out, int out_size, void* d_ws, size_t ws_size,
                              hipStream_t stream) {
    const unsigned short* X0 = (const unsigned short*)d_in[0];
    const int* ei = (const int*)d_in[1];
    const unsigned short* W1 = (const unsigned short*)d_in[2];
    const unsigned short* W2 = (const unsigned short*)d_in[4];
    const unsigned short* g1 = (const unsigned short*)d_in[6];
    const unsigned short* be1 = (const unsigned short*)d_in[7];
    const unsigned short* g2 = (const unsigned short*)d_in[8];
    const unsigned short* be2 = (const unsigned short*)d_in[9];
    float* OUT = (float*)d_out;

    int N = in_sizes[0] / HDIM;
    int E = in_sizes[1] / 2;
    int total = N * HDIM;
    int applyb = (total + 255) / 256;

    bool ok = (n_in == 10) && (N > 0) && (in_sizes[0] == N * HDIM) && (E > 0)
           && (in_sizes[2] == HDIM * HDIM) && (in_sizes[4] == HDIM * HDIM)
           && (in_sizes[6] == HDIM) && (in_sizes[9] == HDIM) && (out_size == total);
    if (!ok) { fill_f32<<<applyb, 256, 0, stream>>>(OUT, total, -100.0f); return; }

    size_t need = (size_t)N * 28 + 2048 + 16 + 1024 + (size_t)E * 12
                + (size_t)total * 4 + 65536 + 1024;
    if (ws_size < need) { fill_f32<<<applyb, 256, 0, stream>>>(OUT, total, -300.0f); return; }

    char* w = (char*)d_ws;
    int* cnt = (int*)w;       w += (size_t)N * 4;       // [zero region start]
    float* stats = (float*)w; w += 2048;                // colsum|colsq|scale|shift
    int* flags = (int*)w;     w += 16;
    int* bsum = (int*)w;      w += 1024;
    float* dinv = (float*)w;  w += (size_t)N * 4;
    int* cursor = (int*)w;    w += (size_t)N * 4;
    w = (char*)(((uintptr_t)w + 15) & ~(uintptr_t)15);
    int4* meta = (int4*)w;    w += (size_t)N * 16;
    int* s32 = (int*)w;       w += (size_t)E * 4;
    int* d32 = (int*)w;       w += (size_t)E * 4;
    int* csr = (int*)w;       w += (size_t)E * 4;
    unsigned short* Hb = (unsigned short*)w;  w += (size_t)total * 2;
    unsigned short* AGG = (unsigned short*)w; w += (size_t)total * 2;
    unsigned short* Wt1 = (unsigned short*)w; w += (size_t)HDIM * HDIM * 2;
    unsigned short* Wt2 = (unsigned short*)w; w += (size_t)HDIM * HDIM * 2;

    float* colsum = stats;
    float* colsq = stats + 128;
    float* scale = stats + 256;
    float* shift = stats + 384;

    int nb = (N + 255) / 256;
    int ebl = (E + 255) / 256;
    int gemmb = (N + 63) / 64;
    float invn = 1.0f / (float)N;

    detect_k<<<1, 256, 0, stream>>>(X0, flags);
    norm_w_t2<<<128, 256, 0, stream>>>(W1, W2, Wt1, Wt2, flags);
    zero_i32<<<(N + 512 + 255) / 256, 256, 0, stream>>>(cnt, N + 512);

    edges_norm<<<ebl, 256, 0, stream>>>(ei, s32, d32, cnt, E, N);
    scan1<<<nb, 256, 0, stream>>>(cnt, bsum, dinv, N);
    scan2<<<1, 256, 0, stream>>>(bsum, nb);
    scan3<<<nb, 256, 0, stream>>>(cnt, bsum, meta, cursor, N);
    scatter_k<<<ebl, 256, 0, stream>>>(s32, d32, cursor, csr, E);

    // layer 1 (Hb = dinv * X @ W1)
    gemm_mfma<<<gemmb, 256, 0, stream>>>(X0, Wt1, Hb, flags, -1, scale, shift, dinv, N);
    agg_stats<<<2048, 256, 0, stream>>>(Hb, meta, csr, AGG, colsum, colsq, N);
    bn_fin<<<1, 256, 0, stream>>>(colsum, colsq, g1, be1, flags, scale, shift, invn);

    // layer 2 (BN+ReLU fused into gemm A-staging; Hb = dinv * relu(bn(AGG)) @ W2)
    gemm_mfma<<<gemmb, 256, 0, stream>>>(AGG, Wt2, Hb, flags, 2, scale, shift, dinv, N);
    agg_stats<<<2048, 256, 0, stream>>>(Hb, meta, csr, AGG, colsum, colsq, N);
    bn_fin<<<1, 256, 0, stream>>>(colsum, colsq, g2, be2, flags, scale, shift, invn);
    bn_apply_f32<<<(total / 8 + 255) / 256, 256, 0, stream>>>(AGG, scale, shift, OUT, total / 8);
}